// Round 17
// baseline (482.657 us; speedup 1.0000x reference)
//
#include <hip/hip_runtime.h>
#include <hip/hip_bf16.h>

constexpr int N = 50000;
constexpr int E = 800000;
constexpr int D = 128;
constexpr int H = 4;
constexpr int C = 32;
constexpr int L = 3;
constexpr int E2 = E + N;           // edges + self loops
constexpr float SLOPE = 0.2f;
constexpr float BN_EPS = 1e-5f;
constexpr float LOG2E = 1.4426950408889634f;
constexpr int TILES = (N + 63) / 64;                 // 782 row tiles

typedef __attribute__((ext_vector_type(8))) short bf16x8_t;   // 8 bf16 (4 VGPRs)
typedef __attribute__((ext_vector_type(4))) float f32x4_t;    // MFMA C/D
typedef __attribute__((ext_vector_type(2))) float v2f;        // packed fp32 (v_pk_*)

using hbf = __hip_bfloat16;

__device__ __forceinline__ float fast_exp2(float x) { return __builtin_amdgcn_exp2f(x); }

__device__ __forceinline__ short f2bf(float v) {
    hbf h = __float2bfloat16(v);
    return *reinterpret_cast<short*>(&h);
}
__device__ __forceinline__ v2f bfpair_to_v2(unsigned int u) {
    v2f r;
    r.x = __uint_as_float(u << 16);
    r.y = __uint_as_float(u & 0xffff0000u);
    return r;
}

// ---------- CSR build (r15-proven path) ----------
__global__ void count_kernel(const int* __restrict__ ei, int* __restrict__ counts) {
    int i = blockIdx.x * blockDim.x + threadIdx.x;
    if (i >= E2) return;
    int dst = (i < E) ? ei[E + i] : (i - E);
    atomicAdd(&counts[dst], 1);
}

__global__ __launch_bounds__(512) void scan_block_kernel(const int* __restrict__ counts,
                                                         int* __restrict__ row_ptr,
                                                         int* __restrict__ blk_sums) {
    __shared__ int s[512];
    int t = threadIdx.x;
    int i = blockIdx.x * 512 + t;
    int v = (i < N) ? counts[i] : 0;
    s[t] = v;
    __syncthreads();
    for (int off = 1; off < 512; off <<= 1) {
        int add = (t >= off) ? s[t - off] : 0;
        __syncthreads();
        s[t] += add;
        __syncthreads();
    }
    if (i < N) row_ptr[i] = s[t] - v;                 // exclusive within block
    if (t == 511) blk_sums[blockIdx.x] = s[511];
}

__global__ __launch_bounds__(128) void scan_sums_kernel(int* __restrict__ blk, int nb) {
    __shared__ int s[128];
    int t = threadIdx.x;
    int v = (t < nb) ? blk[t] : 0;
    s[t] = v;
    __syncthreads();
    for (int off = 1; off < 128; off <<= 1) {
        int add = (t >= off) ? s[t - off] : 0;
        __syncthreads();
        s[t] += add;
        __syncthreads();
    }
    if (t < nb) blk[t] = s[t] - v;                    // exclusive block offsets
}

__global__ void scan_add_kernel(int* __restrict__ row_ptr, const int* __restrict__ blk) {
    int i = blockIdx.x * blockDim.x + threadIdx.x;
    if (i < N) row_ptr[i] += blk[i >> 9];
    if (i == 0) row_ptr[N] = E2;
}

__global__ void scatter_kernel(const int* __restrict__ ei, const int* __restrict__ row_ptr,
                               int* __restrict__ wp, int* __restrict__ col_idx) {
    int i = blockIdx.x * blockDim.x + threadIdx.x;
    if (i >= E2) return;
    int src, dst;
    if (i < E) { src = ei[i]; dst = ei[E + i]; }
    else       { src = i - E; dst = i - E; }
    int pos = row_ptr[dst] + atomicAdd(&wp[dst], 1);
    col_idx[pos] = src;
}

// ---------- pack 10 weight matrices into MFMA B-fragment order (hi bf16 only) ----------
// B frag for 16x16x32: lane holds B[k = ks*32 + (lane>>4)*8 + j][n = nb*16 + (lane&15)],
// j=0..7. Packed index: (mat*2048 + (ks*8+nb)*64 + lane)*8 + j  -> lane-contiguous 16B.
__global__ __launch_bounds__(256) void pack_w_kernel(
        const float* __restrict__ Wl, const float* __restrict__ Wr,
        const float* __restrict__ Wres, const float* __restrict__ Wout,
        hbf* __restrict__ Wph) {
    int gid = blockIdx.x * 256 + threadIdx.x;        // 10 * 16384
    int mat = gid >> 14;
    int d = gid & 16383;
    const float* W;
    if (mat < 3)      W = Wl + (size_t)mat * 16384;
    else if (mat < 6) W = Wr + (size_t)(mat - 3) * 16384;
    else if (mat < 9) W = Wres + (size_t)(mat - 6) * 16384;
    else              W = Wout;
    int j = d & 7, lane = (d >> 3) & 63, nb = (d >> 9) & 7, ks = d >> 12;
    int k = ks * 32 + ((lane >> 4) * 8) + j;
    int n = nb * 16 + (lane & 15);
    Wph[gid] = __float2bfloat16(W[k * D + n]);
}

// ---------- fused 3-matrix MFMA GEMM, one 64-row tile per block ----------
// X = leaky(bn(x)) if sums else x; bn scale/shift derived in-block from sums+gamma+beta.
// xl = bf16(X@Wl), xr = bf16(X@Wr), y = X@Wres + bias.  In-place-safe (x == y): tile
// snapshot into LDS before any store; each tile owned by one block.
// Wave w owns n-blocks {2w, 2w+1}; B frags (24) in VGPRs, loaded once per block.
// 2-term split: X@W ~= Xh@Wh + Xl@Wh (W bf16-rounded).
__global__ __launch_bounds__(256) void gemm3_mfma_kernel(
        const float* x, const float* __restrict__ sums,
        const float* __restrict__ gamma, const float* __restrict__ beta,
        const hbf* __restrict__ Wph,
        int mL, int mR, int mS, const float* __restrict__ bias,
        hbf* __restrict__ xl, hbf* __restrict__ xr, float* y) {
    __shared__ float xs[64][133];                     // +5 pad: 2-way max bank aliasing
    __shared__ float ssl[2][128];                     // bn scale/shift
    int t = threadIdx.x;
    int wave = t >> 6;
    int lane = t & 63;
    int nb0 = wave * 2;                               // this wave's two n-blocks
    int row0 = blockIdx.x * 64;

    if (sums && t < 128) {                            // fold of old bn_finalize
        float mean = sums[t] * (1.0f / N);
        float var = fmaxf(sums[D + t] * (1.0f / N) - mean * mean, 0.f);
        float sc = gamma[t] * rsqrtf(var + BN_EPS);
        ssl[0][t] = sc;
        ssl[1][t] = beta[t] - mean * sc;
    }

    const bf16x8_t* B = (const bf16x8_t*)Wph;
    bf16x8_t bL[4][2], bR[4][2], bS[4][2];            // 24 frags = 96 VGPRs, loaded once
#pragma unroll
    for (int ks = 0; ks < 4; ++ks)
#pragma unroll
        for (int j = 0; j < 2; ++j) {
            int bo = (ks * 8 + nb0 + j) * 64 + lane;
            bL[ks][j] = B[mL * 2048 + bo];
            bR[ks][j] = B[mR * 2048 + bo];
            bS[ks][j] = B[mS * 2048 + bo];
        }
    __syncthreads();                                  // ssl visible

    int cg = (t & 31) * 4;                            // staging col group
    {
        float sc_[4] = {1.f, 1.f, 1.f, 1.f}, sh_[4] = {0.f, 0.f, 0.f, 0.f};
        if (sums) {
#pragma unroll
            for (int j = 0; j < 4; ++j) { sc_[j] = ssl[0][cg + j]; sh_[j] = ssl[1][cg + j]; }
        }
        const float4* x4 = (const float4*)(x + (size_t)row0 * D);
        for (int i = t; i < 64 * 32; i += 256) {
            int r = i >> 5;
            float4 v = make_float4(0.f, 0.f, 0.f, 0.f);
            if (row0 + r < N) {
                v = x4[i];
                if (sums) {
                    v.x = fmaf(v.x, sc_[0], sh_[0]); v.x = fmaxf(v.x, SLOPE * v.x);
                    v.y = fmaf(v.y, sc_[1], sh_[1]); v.y = fmaxf(v.y, SLOPE * v.y);
                    v.z = fmaf(v.z, sc_[2], sh_[2]); v.z = fmaxf(v.z, SLOPE * v.z);
                    v.w = fmaf(v.w, sc_[3], sh_[3]); v.w = fmaxf(v.w, SLOPE * v.w);
                }
            }
            *(float4*)&xs[r][cg] = v;
        }
    }
    __syncthreads();

    int col = lane & 15;
    int koff = (lane >> 4) * 8;
    for (int mm = 0; mm < 4; ++mm) {
        int mrow = mm * 16 + (lane & 15);
        f32x4_t aL[2], aR[2], aS[2];
#pragma unroll
        for (int j = 0; j < 2; ++j) {
            aL[j] = (f32x4_t)0.f; aR[j] = (f32x4_t)0.f; aS[j] = (f32x4_t)0.f;
        }
#pragma unroll
        for (int ks = 0; ks < 4; ++ks) {
            const float* src = &xs[mrow][ks * 32 + koff];
            float4 f0 = *(const float4*)src;
            float4 f1 = *(const float4*)(src + 4);
            float f[8] = {f0.x, f0.y, f0.z, f0.w, f1.x, f1.y, f1.z, f1.w};
            bf16x8_t ah, al;
#pragma unroll
            for (int j = 0; j < 8; ++j) {
                short hi = f2bf(f[j]);
                unsigned int hu = ((unsigned int)(unsigned short)hi) << 16;
                ah[j] = hi;
                al[j] = f2bf(f[j] - __uint_as_float(hu));
            }
#pragma unroll
            for (int j = 0; j < 2; ++j) {
                aL[j] = __builtin_amdgcn_mfma_f32_16x16x32_bf16(ah, bL[ks][j], aL[j], 0, 0, 0);
                aL[j] = __builtin_amdgcn_mfma_f32_16x16x32_bf16(al, bL[ks][j], aL[j], 0, 0, 0);
                aR[j] = __builtin_amdgcn_mfma_f32_16x16x32_bf16(ah, bR[ks][j], aR[j], 0, 0, 0);
                aR[j] = __builtin_amdgcn_mfma_f32_16x16x32_bf16(al, bR[ks][j], aR[j], 0, 0, 0);
                aS[j] = __builtin_amdgcn_mfma_f32_16x16x32_bf16(ah, bS[ks][j], aS[j], 0, 0, 0);
                aS[j] = __builtin_amdgcn_mfma_f32_16x16x32_bf16(al, bS[ks][j], aS[j], 0, 0, 0);
            }
        }
        // C/D layout: col = lane&15, row = (lane>>4)*4 + r
        int rowq = row0 + mm * 16 + (lane >> 4) * 4;
#pragma unroll
        for (int j = 0; j < 2; ++j) {
            int n = (nb0 + j) * 16 + col;
            float bv = bias[n];
#pragma unroll
            for (int r = 0; r < 4; ++r) {
                int row = rowq + r;
                if (row < N) {
                    xl[(size_t)row * D + n] = __float2bfloat16(aL[j][r]);
                    xr[(size_t)row * D + n] = __float2bfloat16(aR[j][r]);
                    y[(size_t)row * D + n]  = aS[j][r] + bv;
                }
            }
        }
    }
}

// ---------- final linear via MFMA, same structure (BN+leaky on load) ----------
__global__ __launch_bounds__(256) void gemm_out_mfma_kernel(
        const float* __restrict__ x, const float* __restrict__ sums,
        const float* __restrict__ gamma, const float* __restrict__ beta,
        const hbf* __restrict__ Wph, const float* __restrict__ b,
        float* __restrict__ out) {
    __shared__ float xs[64][133];
    __shared__ float ssl[2][128];
    int t = threadIdx.x;
    int wave = t >> 6;
    int lane = t & 63;
    int nb0 = wave * 2;
    int row0 = blockIdx.x * 64;

    if (t < 128) {
        float mean = sums[t] * (1.0f / N);
        float var = fmaxf(sums[D + t] * (1.0f / N) - mean * mean, 0.f);
        float sc = gamma[t] * rsqrtf(var + BN_EPS);
        ssl[0][t] = sc;
        ssl[1][t] = beta[t] - mean * sc;
    }

    const bf16x8_t* B = (const bf16x8_t*)Wph + 9 * 2048;      // matrix 9 = Wout
    bf16x8_t bW[4][2];
#pragma unroll
    for (int ks = 0; ks < 4; ++ks)
#pragma unroll
        for (int j = 0; j < 2; ++j)
            bW[ks][j] = B[(ks * 8 + nb0 + j) * 64 + lane];
    __syncthreads();

    int cg = (t & 31) * 4;
    {
        float sc_[4], sh_[4];
#pragma unroll
        for (int j = 0; j < 4; ++j) { sc_[j] = ssl[0][cg + j]; sh_[j] = ssl[1][cg + j]; }
        const float4* x4 = (const float4*)(x + (size_t)row0 * D);
        for (int i = t; i < 64 * 32; i += 256) {
            int r = i >> 5;
            float4 v = make_float4(0.f, 0.f, 0.f, 0.f);
            if (row0 + r < N) {
                v = x4[i];
                v.x = fmaf(v.x, sc_[0], sh_[0]); v.x = fmaxf(v.x, SLOPE * v.x);
                v.y = fmaf(v.y, sc_[1], sh_[1]); v.y = fmaxf(v.y, SLOPE * v.y);
                v.z = fmaf(v.z, sc_[2], sh_[2]); v.z = fmaxf(v.z, SLOPE * v.z);
                v.w = fmaf(v.w, sc_[3], sh_[3]); v.w = fmaxf(v.w, SLOPE * v.w);
            }
            *(float4*)&xs[r][cg] = v;
        }
    }
    __syncthreads();

    int col = lane & 15;
    int koff = (lane >> 4) * 8;
    for (int mm = 0; mm < 4; ++mm) {
        int mrow = mm * 16 + (lane & 15);
        f32x4_t acc[2];
        acc[0] = (f32x4_t)0.f; acc[1] = (f32x4_t)0.f;
#pragma unroll
        for (int ks = 0; ks < 4; ++ks) {
            const float* src = &xs[mrow][ks * 32 + koff];
            float4 f0 = *(const float4*)src;
            float4 f1 = *(const float4*)(src + 4);
            float f[8] = {f0.x, f0.y, f0.z, f0.w, f1.x, f1.y, f1.z, f1.w};
            bf16x8_t ah, al;
#pragma unroll
            for (int j = 0; j < 8; ++j) {
                short hi = f2bf(f[j]);
                unsigned int hu = ((unsigned int)(unsigned short)hi) << 16;
                ah[j] = hi;
                al[j] = f2bf(f[j] - __uint_as_float(hu));
            }
#pragma unroll
            for (int j = 0; j < 2; ++j) {
                acc[j] = __builtin_amdgcn_mfma_f32_16x16x32_bf16(ah, bW[ks][j], acc[j], 0, 0, 0);
                acc[j] = __builtin_amdgcn_mfma_f32_16x16x32_bf16(al, bW[ks][j], acc[j], 0, 0, 0);
            }
        }
        int rowq = row0 + mm * 16 + (lane >> 4) * 4;
#pragma unroll
        for (int j = 0; j < 2; ++j) {
            int n = (nb0 + j) * 16 + col;
            float bv = b[n];
#pragma unroll
            for (int r = 0; r < 4; ++r) {
                int row = rowq + r;
                if (row < N) out[(size_t)row * D + n] = acc[j][r] + bv;
            }
        }
    }
}

// ---------- GATv2 aggregation: wave/node, FOUR edges per wave ----------
// Lane = (q=lane>>4, sub=lane&15): sub -> channels 8sub..8sub+7 (uint4 = 16B gather),
// q -> edge idx+q of each group. Head = 4 sublanes -> 2-level shuffle tree (xor 1,2).
// Tail folded into the main loop: indices clamped, weight masked 0 for idx+q >= end
// (masked quarters never contaminate others: reduce is within-quarter). Cross-quarter
// combine (l, acc) at the end via shfl_xor 16/32. 2-level pipeline: col_idx for each
// buffer's next refill kept in registers (distance 16), data refilled at distance 8.
// Scalars only (r10: dynamic indexing demotes arrays to LDS). No online max (scores
// BN-bounded). log2-domain scores -> exp2.
__global__ __launch_bounds__(256) void gat_kernel(
        const hbf* __restrict__ xl, const hbf* __restrict__ xr,
        float* y, const int* __restrict__ row_ptr,
        const int* __restrict__ col_idx, const float* __restrict__ att) {
    int wave = threadIdx.x >> 6;
    int lane = threadIdx.x & 63;
    int q   = lane >> 4;                              // edge slot within group of 4
    int sub = lane & 15;                              // channels 8*sub .. 8*sub+7
    int v = blockIdx.x * 4 + wave;
    const uint4* xlp = (const uint4*)xl;              // 16 uint4 per row
    const uint4* xrp = (const uint4*)xr;
    uint4 xru = xrp[(size_t)v * 16 + sub];
    v2f xr0 = bfpair_to_v2(xru.x), xr1 = bfpair_to_v2(xru.y);
    v2f xr2 = bfpair_to_v2(xru.z), xr3 = bfpair_to_v2(xru.w);
    float4 a4a = ((const float4*)att)[2 * sub];       // head = sub/4
    float4 a4b = ((const float4*)att)[2 * sub + 1];
    v2f a0; a0.x = a4a.x * LOG2E; a0.y = a4a.y * LOG2E;
    v2f a1; a1.x = a4a.z * LOG2E; a1.y = a4a.w * LOG2E;
    v2f a2; a2.x = a4b.x * LOG2E; a2.y = a4b.y * LOG2E;
    v2f a3; a3.x = a4b.z * LOG2E; a3.y = a4b.w * LOG2E;
    int beg = row_ptr[v], end = row_ptr[v + 1];
    float l = 0.f;
    v2f ac0 = {0.f, 0.f}, ac1 = {0.f, 0.f}, ac2 = {0.f, 0.f}, ac3 = {0.f, 0.f};

    // pipeline: u0/u1 = data for groups G,G+1; c0/c1 = col_idx for their refills
    uint4 u0 = xlp[(size_t)col_idx[min(beg + q, end - 1)] * 16 + sub];
    uint4 u1 = xlp[(size_t)col_idx[min(beg + 4 + q, end - 1)] * 16 + sub];
    int   c0 = col_idx[min(beg + 8 + q, end - 1)];
    int   c1 = col_idx[min(beg + 12 + q, end - 1)];

    int idx = beg;
    auto process4 = [&](uint4& buf, int& cid) {
        uint4 d = buf;
        buf = xlp[(size_t)cid * 16 + sub];            // refill at distance 8 (no chain)
        cid = col_idx[min(idx + 16 + q, end - 1)];    // col_idx at distance 16
        v2f x0 = bfpair_to_v2(d.x), x1 = bfpair_to_v2(d.y);
        v2f x2 = bfpair_to_v2(d.z), x3 = bfpair_to_v2(d.w);
        v2f p0 = x0 + xr0, p1 = x1 + xr1;             // v_pk_add_f32
        v2f p2 = x2 + xr2, p3 = x3 + xr3;
        p0 = __builtin_elementwise_max(p0, p0 * SLOPE);
        p1 = __builtin_elementwise_max(p1, p1 * SLOPE);
        p2 = __builtin_elementwise_max(p2, p2 * SLOPE);
        p3 = __builtin_elementwise_max(p3, p3 * SLOPE);
        v2f tt = p0 * a0;
        tt = p1 * a1 + tt;
        tt = p2 * a2 + tt;
        tt = p3 * a3 + tt;
        float s = tt.x + tt.y;
        s += __shfl_xor(s, 1);                        // head reduce (4 sublanes)
        s += __shfl_xor(s, 2);
        float w = (idx + q < end) ? fast_exp2(s) : 0.f;
        l += w;
        ac0 = x0 * w + ac0;                           // v_pk_fma_f32
        ac1 = x1 * w + ac1;
        ac2 = x2 * w + ac2;
        ac3 = x3 * w + ac3;
    };

    while (idx < end) {
        process4(u0, c0);
        idx += 4;
        if (idx >= end) break;
        process4(u1, c1);
        idx += 4;
    }
    // combine quarters (each held every 4th edge)
    l += __shfl_xor(l, 16);  l += __shfl_xor(l, 32);
    ac0.x += __shfl_xor(ac0.x, 16); ac0.x += __shfl_xor(ac0.x, 32);
    ac0.y += __shfl_xor(ac0.y, 16); ac0.y += __shfl_xor(ac0.y, 32);
    ac1.x += __shfl_xor(ac1.x, 16); ac1.x += __shfl_xor(ac1.x, 32);
    ac1.y += __shfl_xor(ac1.y, 16); ac1.y += __shfl_xor(ac1.y, 32);
    ac2.x += __shfl_xor(ac2.x, 16); ac2.x += __shfl_xor(ac2.x, 32);
    ac2.y += __shfl_xor(ac2.y, 16); ac2.y += __shfl_xor(ac2.y, 32);
    ac3.x += __shfl_xor(ac3.x, 16); ac3.x += __shfl_xor(ac3.x, 32);
    ac3.y += __shfl_xor(ac3.y, 16); ac3.y += __shfl_xor(ac3.y, 32);
    if (q == 0) {
        float rl = 1.f / l;
        float* yp = y + (size_t)v * D + 8 * sub;
        float4 y0 = *(float4*)yp;
        float4 y1 = *(float4*)(yp + 4);
        y0.x = fmaf(ac0.x, rl, y0.x);                 // agg + res(+bias)
        y0.y = fmaf(ac0.y, rl, y0.y);
        y0.z = fmaf(ac1.x, rl, y0.z);
        y0.w = fmaf(ac1.y, rl, y0.w);
        y1.x = fmaf(ac2.x, rl, y1.x);
        y1.y = fmaf(ac2.y, rl, y1.y);
        y1.z = fmaf(ac3.x, rl, y1.z);
        y1.w = fmaf(ac3.y, rl, y1.w);
        *(float4*)yp = y0;
        *(float4*)(yp + 4) = y1;
    }
}

// ---------- BatchNorm stats: coalesced float4, LDS reduce, atomics ----------
__global__ __launch_bounds__(256) void bn_stats_kernel(const float* __restrict__ y,
                                                       float* __restrict__ sums) {
    __shared__ float ls[256][4];
    __shared__ float ls2[256][4];
    int t = threadIdx.x;
    float4 s = make_float4(0.f, 0.f, 0.f, 0.f);
    float4 s2 = make_float4(0.f, 0.f, 0.f, 0.f);
    const float4* y4 = (const float4*)y;
    for (int i = blockIdx.x * 256 + t; i < N * D / 4; i += gridDim.x * 256) {
        float4 v = y4[i];                             // cols 4*(t&31)..+3 (fixed)
        s.x += v.x; s.y += v.y; s.z += v.z; s.w += v.w;
        s2.x = fmaf(v.x, v.x, s2.x); s2.y = fmaf(v.y, v.y, s2.y);
        s2.z = fmaf(v.z, v.z, s2.z); s2.w = fmaf(v.w, v.w, s2.w);
    }
    ls[t][0] = s.x;  ls[t][1] = s.y;  ls[t][2] = s.z;  ls[t][3] = s.w;
    ls2[t][0] = s2.x; ls2[t][1] = s2.y; ls2[t][2] = s2.z; ls2[t][3] = s2.w;
    __syncthreads();
    if (t < D) {
        int g = t >> 2, e = t & 3;
        float a = 0.f, b = 0.f;
#pragma unroll
        for (int j = 0; j < 8; ++j) {
            a += ls[g + 32 * j][e];
            b += ls2[g + 32 * j][e];
        }
        atomicAdd(&sums[t], a);
        atomicAdd(&sums[D + t], b);
    }
}

extern "C" void kernel_launch(void* const* d_in, const int* in_sizes, int n_in,
                              void* d_out, int out_size, void* d_ws, size_t ws_size,
                              hipStream_t stream) {
    const float* x_in  = (const float*)d_in[0];
    const int*   ei    = (const int*)d_in[1];
    const float* Wl    = (const float*)d_in[2];
    const float* Wr    = (const float*)d_in[3];
    const float* att   = (const float*)d_in[4];
    const float* bias  = (const float*)d_in[5];
    const float* Wres  = (const float*)d_in[6];
    const float* gamma = (const float*)d_in[7];
    const float* beta  = (const float*)d_in[8];
    const float* Wout  = (const float*)d_in[9];
    const float* bout  = (const float*)d_in[10];
    float* out = (float*)d_out;

    char* ws = (char*)d_ws;
    size_t off = 0;
    auto alloc = [&](size_t bytes) {
        void* p = ws + off;
        off = (off + bytes + 255) & ~(size_t)255;
        return p;
    };
    hbf*   xl       = (hbf*)alloc((size_t)N * D * sizeof(hbf));
    hbf*   xr       = (hbf*)alloc((size_t)N * D * sizeof(hbf));
    float* y        = (float*)alloc((size_t)N * D * sizeof(float));
    hbf*   Wph      = (hbf*)alloc((size_t)10 * D * D * sizeof(hbf));
    int*   row_ptr  = (int*)alloc((size_t)(N + 1) * sizeof(int));
    int*   col_idx  = (int*)alloc((size_t)E2 * sizeof(int));
    int*   counts   = (int*)alloc((size_t)N * sizeof(int));   // reused as write ptr
    int*   blk_sums = (int*)alloc(128 * sizeof(int));
    float* sums     = (float*)alloc(3 * 2 * D * sizeof(float));  // per-layer bn sums

    const int NB = (N + 511) / 512;                  // 98 scan blocks

    // CSR build + weight packing (r15-proven path)
    (void)hipMemsetAsync(counts, 0, (size_t)N * sizeof(int), stream);
    (void)hipMemsetAsync(sums, 0, 3 * 2 * D * sizeof(float), stream);
    count_kernel<<<(E2 + 255) / 256, 256, 0, stream>>>(ei, counts);
    pack_w_kernel<<<10 * 16384 / 256, 256, 0, stream>>>(Wl, Wr, Wres, Wout, Wph);
    scan_block_kernel<<<NB, 512, 0, stream>>>(counts, row_ptr, blk_sums);
    scan_sums_kernel<<<1, 128, 0, stream>>>(blk_sums, NB);
    scan_add_kernel<<<(N + 255) / 256, 256, 0, stream>>>(row_ptr, blk_sums);
    (void)hipMemsetAsync(counts, 0, (size_t)N * sizeof(int), stream);
    scatter_kernel<<<(E2 + 255) / 256, 256, 0, stream>>>(ei, row_ptr, counts, col_idx);

    for (int i = 0; i < L; ++i) {
        const float* xin = (i == 0) ? x_in : y;      // in-place (tile snapshot) for 1,2
        const float* sm  = (i == 0) ? nullptr : sums + (size_t)(i - 1) * 2 * D;
        const float* ga  = (i == 0) ? nullptr : gamma + (size_t)(i - 1) * D;
        const float* be  = (i == 0) ? nullptr : beta + (size_t)(i - 1) * D;
        gemm3_mfma_kernel<<<TILES, 256, 0, stream>>>(xin, sm, ga, be, Wph,
                                                     i, 3 + i, 6 + i,
                                                     bias + (size_t)i * D, xl, xr, y);
        gat_kernel<<<N / 4, 256, 0, stream>>>(xl, xr, y, row_ptr, col_idx,
                                              att + (size_t)i * H * C);
        bn_stats_kernel<<<512, 256, 0, stream>>>(y, sums + (size_t)i * 2 * D);
    }

    gemm_out_mfma_kernel<<<TILES, 256, 0, stream>>>(y, sums + (size_t)2 * 2 * D,
                                                    gamma + (size_t)2 * D,
                                                    beta + (size_t)2 * D, Wph, bout, out);
}